// Round 12
// baseline (196.096 us; speedup 1.0000x reference)
//
#include <hip/hip_runtime.h>
#include <hip/hip_bf16.h>
#include <cstdint>
#include <cstddef>

// Problem constants
#define SEQ   2048
#define HID   2048
#define NH    32
#define NKVH  8
#define HD    64
#define KVDIM (NKVH * HD)   // 512

typedef __bf16 bf16_t;
typedef __bf16 bf16x8 __attribute__((ext_vector_type(8)));
typedef float  f32x4  __attribute__((ext_vector_type(4)));
typedef unsigned int u32x2 __attribute__((ext_vector_type(2)));
typedef unsigned int u32x4 __attribute__((ext_vector_type(4)));

// log2(10000)/32  (RoPE: theta^(-d/32) = exp2(-d*L))
#define ROPE_L 0.4152410118609203f

#if __has_builtin(__builtin_amdgcn_exp2f)
#define QSCALE 0.18033688011112043f
#define EXPFN(x) __builtin_amdgcn_exp2f(x)
#else
#define QSCALE 0.125f
#define EXPFN(x) __expf(x)
#endif

// counted-vmcnt barrier primitives (T4): wave waits for its OLDEST stage's
// loads only; the next stage's loads stay in flight across the barrier.
#define WAITV4  do { asm volatile("s_waitcnt vmcnt(4)" ::: "memory"); \
                     __builtin_amdgcn_sched_barrier(0); \
                     __builtin_amdgcn_s_barrier(); } while (0)
#define WAITV0  do { asm volatile("s_waitcnt vmcnt(0)" ::: "memory"); \
                     __builtin_amdgcn_sched_barrier(0); \
                     __builtin_amdgcn_s_barrier(); } while (0)
#define BAR     __builtin_amdgcn_s_barrier()

__device__ __forceinline__ bf16x8 load8(const float* p) {
    const float4 lo = *(const float4*)p;
    const float4 hi = *(const float4*)(p + 4);
    bf16x8 r;
    r[0] = (bf16_t)lo.x; r[1] = (bf16_t)lo.y; r[2] = (bf16_t)lo.z; r[3] = (bf16_t)lo.w;
    r[4] = (bf16_t)hi.x; r[5] = (bf16_t)hi.y; r[6] = (bf16_t)hi.z; r[7] = (bf16_t)hi.w;
    return r;
}

// async global->LDS, 16B per lane; LDS dest = wave-uniform base + lane*16
__device__ __forceinline__ void load_lds16(const bf16_t* g, bf16_t* l) {
    __builtin_amdgcn_global_load_lds((const __attribute__((address_space(1))) void*)g,
                                     (__attribute__((address_space(3))) void*)l,
                                     16, 0, 0);
}

// pack two f32 -> one dword of 2 bf16 (no builtin on gfx950; T12 recipe, m240)
__device__ __forceinline__ unsigned int cvt_pk_bf16(float lo, float hi) {
    unsigned int r;
    asm("v_cvt_pk_bf16_f32 %0, %1, %2" : "=v"(r) : "v"(lo), "v"(hi));
    return r;
}

// ---------------------------------------------------------------------------
// One-shot fp32 -> bf16 conversion of all GEMM operands.
// ---------------------------------------------------------------------------
#define NX  (SEQ * HID)          // 4M
#define NWQ (NH * HD * HID)      // 4M
#define NWK (KVDIM * HID)        // 1M
#define NWV (KVDIM * HID)        // 1M
#define NWO (HID * NH * HD)      // 4M
#define NTOT (NX + NWQ + NWK + NWV + NWO)   // 14M

__global__ __launch_bounds__(256) void cvt_all(const float* __restrict__ X,
                                               const float* __restrict__ Wq,
                                               const float* __restrict__ Wk,
                                               const float* __restrict__ Wv,
                                               const float* __restrict__ Wo,
                                               bf16_t* __restrict__ Xb,
                                               bf16_t* __restrict__ Wqb,
                                               bf16_t* __restrict__ Wkb,
                                               bf16_t* __restrict__ Wvb,
                                               bf16_t* __restrict__ Wob)
{
    size_t i = ((size_t)blockIdx.x * 256 + threadIdx.x) * 8;
    if (i >= NTOT) return;
    const size_t E0 = NX, E1 = E0 + NWQ, E2 = E1 + NWK, E3 = E2 + NWV;
    const float* s; bf16_t* d; size_t off;
    if (i < E0)      { s = X;  d = Xb;  off = i; }
    else if (i < E1) { s = Wq; d = Wqb; off = i - E0; }
    else if (i < E2) { s = Wk; d = Wkb; off = i - E1; }
    else if (i < E3) { s = Wv; d = Wvb; off = i - E2; }
    else             { s = Wo; d = Wob; off = i - E3; }
    *(bf16x8*)(d + off) = load8(s + off);
}

// ---------------------------------------------------------------------------
// Swizzled-tile convention (T2, both-sides, rule #21):
//   LDS tile = [rows][64] bf16, 128B rows.  Physical 16B slot s of row r
//   holds LOGICAL k-group (s ^ (r&7)).  Staging: linear LDS dest, per-lane
//   pre-swizzled global source.  Reads: slot G ^ (r&7).
//
// XCD swizzle (T1, confirmed R10: qkv 46 -> <40.6us): 1D grid; xcd = bid&7,
// j = bid>>3 indexes a contiguous 2D chunk per XCD so blocks sharing A/B
// panels coalesce in one XCD's L2.
// ---------------------------------------------------------------------------

// ---------------------------------------------------------------------------
// Fused QKV projection + RoPE, 128x128 tiles, 512 threads (8 waves, 4x2
// grid of 32x64 wave-tiles), counted-vmcnt pipeline, XCD-chunked blocks.
// (byte-identical to R10/R11, which passed)
// ---------------------------------------------------------------------------
__global__ __launch_bounds__(512, 4) void qkv_gemm(const bf16_t* __restrict__ Xb,
                                                   const bf16_t* __restrict__ Wqb,
                                                   const bf16_t* __restrict__ Wkb,
                                                   const bf16_t* __restrict__ Wvb,
                                                   bf16_t* __restrict__ Qb,
                                                   bf16_t* __restrict__ Kb,
                                                   bf16_t* __restrict__ Vt)
{
    __shared__ alignas(16) bf16_t sa0[128 * 64], sa1[128 * 64];   // 16KB each
    __shared__ alignas(16) bf16_t sb0[128 * 64], sb1[128 * 64];   // 16KB each
    const int t = threadIdx.x;
    const int lane = t & 63;
    const int w  = t >> 6;               // 0..7
    const int n16 = lane & 15;
    const int q4  = lane >> 4;
    const int wm = (w >> 1) * 32;        // wave tile origin in M (0,32,64,96)
    const int wn = (w & 1) * 64;         // wave tile origin in N (head-aligned)
    f32x4 acc[2][4] = {};

    // ---- T1 XCD-chunked block swizzle: grid 384 = 8 XCDs x (8m x 6n) ----
    const int bid = blockIdx.x;
    const int xcd = bid & 7;
    const int j   = bid >> 3;                    // 0..47
    const int m0 = ((xcd & 1) * 8 + (j & 7)) * 128;     // m-tile 0..15
    const int n0 = ((xcd >> 1) * 6 + (j >> 3)) * 128;   // n-tile 0..23

    const bf16_t* B;
    int mode, nc;
    if (n0 < NH * HD)              { B = Wqb + (size_t)n0 * HID;                     mode = 0; nc = n0; }
    else if (n0 < NH * HD + KVDIM) { B = Wkb + (size_t)(n0 - NH * HD) * HID;         mode = 1; nc = n0 - NH * HD; }
    else                           { B = Wvb + (size_t)(n0 - NH * HD - KVDIM) * HID; mode = 2; nc = n0 - NH * HD - KVDIM; }

    const int lrow8 = lane >> 3;                 // 0..7 (row within 8-row chunk)
    const int lgrp  = (lane & 7) ^ lrow8;        // pre-swizzled source col-group
    const bf16_t* ag = Xb + (size_t)(m0 + w * 16 + lrow8) * HID + lgrp * 8;
    const bf16_t* bg = B  + (size_t)(w * 16 + lrow8) * HID + lgrp * 8;

    auto stage = [&](bf16_t* da, bf16_t* db, int k0) {
        // wave w covers A rows [w*16, w*16+16) and B rows [w*16, w*16+16)
        load_lds16(ag + k0,                      da + (w * 16) * 64);
        load_lds16(ag + (size_t)8 * HID + k0,    da + (w * 16 + 8) * 64);
        load_lds16(bg + k0,                      db + (w * 16) * 64);
        load_lds16(bg + (size_t)8 * HID + k0,    db + (w * 16 + 8) * 64);
    };
    auto mma_step = [&](const bf16_t* sa, const bf16_t* sb) {
#pragma unroll
        for (int kk = 0; kk < 2; ++kk) {
            const int xo = ((kk * 4 + q4) ^ (n16 & 7)) * 8;
            bf16x8 bfrag[4], afrag[2];
#pragma unroll
            for (int j2 = 0; j2 < 4; ++j2)
                bfrag[j2] = *(const bf16x8*)&sb[(wn + j2 * 16 + n16) * 64 + xo];
#pragma unroll
            for (int i = 0; i < 2; ++i)
                afrag[i] = *(const bf16x8*)&sa[(wm + i * 16 + n16) * 64 + xo];
#pragma unroll
            for (int i = 0; i < 2; ++i)
#pragma unroll
                for (int j2 = 0; j2 < 4; ++j2)
                    acc[i][j2] = __builtin_amdgcn_mfma_f32_16x16x32_bf16(afrag[i], bfrag[j2], acc[i][j2], 0, 0, 0);
        }
    };

    // 32 stages of BK=64.  Prologue: stages 0,1.  Loop t issues stage t+2.
    stage(sa0, sb0, 0);
    stage(sa1, sb1, 64);
#pragma unroll 1
    for (int tt = 0; tt < 30; tt += 2) {
        WAITV4;
        mma_step(sa0, sb0);
        BAR;
        stage(sa0, sb0, (tt + 2) * 64);
        WAITV4;
        mma_step(sa1, sb1);
        BAR;
        stage(sa1, sb1, (tt + 3) * 64);
    }
    WAITV4;
    mma_step(sa0, sb0);      // stage 30
    BAR;
    WAITV0;
    mma_step(sa1, sb1);      // stage 31

    if (mode < 2) {
        // ---- RoPE in registers: wave covers one head (wn mult of HD) ----
#pragma unroll
        for (int jt = 0; jt < 2; ++jt) {
            float dd = (float)(jt * 16 + n16);
            float inv = exp2f(-dd * ROPE_L);
#pragma unroll
            for (int i = 0; i < 2; ++i) {
#pragma unroll
                for (int r = 0; r < 4; ++r) {
                    int pos = m0 + wm + i * 16 + q4 * 4 + r;
                    float ang = (float)pos * inv;
                    float sn, cs;
                    sincosf(ang, &sn, &cs);
                    float x1 = acc[i][jt][r], x2 = acc[i][jt + 2][r];
                    acc[i][jt][r]     = x1 * cs - x2 * sn;
                    acc[i][jt + 2][r] = x2 * cs + x1 * sn;
                }
            }
        }
        const float osc = (mode == 0) ? QSCALE : 1.0f;
        bf16_t* dst = (mode == 0) ? Qb : Kb;
        const int ld = (mode == 0) ? NH * HD : KVDIM;
#pragma unroll
        for (int i = 0; i < 2; ++i)
#pragma unroll
            for (int j2 = 0; j2 < 4; ++j2) {
                int row = m0 + wm + i * 16 + q4 * 4;
                int col = nc + wn + j2 * 16 + n16;
#pragma unroll
                for (int r = 0; r < 4; ++r)
                    dst[(size_t)(row + r) * ld + col] = (bf16_t)(acc[i][j2][r] * osc);
            }
    } else {
        // ---- V: store transposed ----
#pragma unroll
        for (int i = 0; i < 2; ++i)
#pragma unroll
            for (int j2 = 0; j2 < 4; ++j2) {
                int row = m0 + wm + i * 16 + q4 * 4;
                int col = nc + wn + j2 * 16 + n16;
#pragma unroll
                for (int r = 0; r < 4; ++r)
                    Vt[(size_t)col * SEQ + row + r] = (bf16_t)acc[i][j2][r];
            }
    }
}

// ---------------------------------------------------------------------------
// O projection: 512-thread 128x128 blocks, grid 256 (1/CU), counted-vmcnt,
// XCD-chunked 8m x 4n blocks.  (byte-identical to R10/R11, which passed)
// ---------------------------------------------------------------------------
__global__ __launch_bounds__(512, 4) void o_gemm(const bf16_t* __restrict__ A,
                                                 const bf16_t* __restrict__ Bw,
                                                 float* __restrict__ C)
{
    __shared__ alignas(16) bf16_t sa0[128 * 64], sa1[128 * 64];
    __shared__ alignas(16) bf16_t sb0[128 * 64], sb1[128 * 64];
    const int t = threadIdx.x;
    const int lane = t & 63;
    const int w  = t >> 6;
    const int n16 = lane & 15;
    const int q4  = lane >> 4;
    const int wm = (w >> 1) * 32;
    const int wn = (w & 1) * 64;
    f32x4 acc[2][4] = {};

    // ---- T1 XCD-chunked swizzle: grid 256 = 8 XCDs x (8m x 4n) ----
    const int bid = blockIdx.x;
    const int xcd = bid & 7;
    const int j   = bid >> 3;                    // 0..31
    const int m0 = ((xcd & 1) * 8 + (j & 7)) * 128;     // m-tile 0..15
    const int n0 = ((xcd >> 1) * 4 + (j >> 3)) * 128;   // n-tile 0..15

    const int lrow8 = lane >> 3;
    const int lgrp  = (lane & 7) ^ lrow8;
    const bf16_t* ag = A  + (size_t)(m0 + w * 16 + lrow8) * HID + lgrp * 8;
    const bf16_t* bg = Bw + (size_t)(n0 + w * 16 + lrow8) * HID + lgrp * 8;

    auto stage = [&](bf16_t* da, bf16_t* db, int k0) {
        load_lds16(ag + k0,                      da + (w * 16) * 64);
        load_lds16(ag + (size_t)8 * HID + k0,    da + (w * 16 + 8) * 64);
        load_lds16(bg + k0,                      db + (w * 16) * 64);
        load_lds16(bg + (size_t)8 * HID + k0,    db + (w * 16 + 8) * 64);
    };
    auto mma_step = [&](const bf16_t* sa, const bf16_t* sb) {
#pragma unroll
        for (int kk = 0; kk < 2; ++kk) {
            const int xo = ((kk * 4 + q4) ^ (n16 & 7)) * 8;
            bf16x8 bfrag[4], afrag[2];
#pragma unroll
            for (int j2 = 0; j2 < 4; ++j2)
                bfrag[j2] = *(const bf16x8*)&sb[(wn + j2 * 16 + n16) * 64 + xo];
#pragma unroll
            for (int i = 0; i < 2; ++i)
                afrag[i] = *(const bf16x8*)&sa[(wm + i * 16 + n16) * 64 + xo];
#pragma unroll
            for (int i = 0; i < 2; ++i)
#pragma unroll
                for (int j2 = 0; j2 < 4; ++j2)
                    acc[i][j2] = __builtin_amdgcn_mfma_f32_16x16x32_bf16(afrag[i], bfrag[j2], acc[i][j2], 0, 0, 0);
        }
    };

    stage(sa0, sb0, 0);
    stage(sa1, sb1, 64);
#pragma unroll 1
    for (int tt = 0; tt < 30; tt += 2) {
        WAITV4;
        mma_step(sa0, sb0);
        BAR;
        stage(sa0, sb0, (tt + 2) * 64);
        WAITV4;
        mma_step(sa1, sb1);
        BAR;
        stage(sa1, sb1, (tt + 3) * 64);
    }
    WAITV4;
    mma_step(sa0, sb0);
    BAR;
    WAITV0;
    mma_step(sa1, sb1);

#pragma unroll
    for (int i = 0; i < 2; ++i)
#pragma unroll
        for (int j2 = 0; j2 < 4; ++j2) {
            int row = m0 + wm + i * 16 + q4 * 4;
            int col = n0 + wn + j2 * 16 + n16;
#pragma unroll
            for (int r = 0; r < 4; ++r)
                C[(size_t)(row + r) * HID + col] = acc[i][j2][r];
        }
}

// ---------------------------------------------------------------------------
// MFMA causal flash attention.  NEW (R12):
//  (a) T4 counted-vmcnt pipeline — the attn loop still used __syncthreads
//      (implicit vmcnt(0) FULL DRAIN every 64-kv tile), the exact pathology
//      removed from the GEMMs in R8.  Now: prologue stages 0,1; loop does
//      WAITV4 -> compute(gh) -> BAR -> stage(gh+2); tail WAITV4 ... WAITV0.
//      Stage issues are block-uniform (depend only on ghmax); compute
//      guards stay wave-local; barrier counts uniform.
//  (b) T1 kvh->XCD pinning: kvh = bid&7 (one KV-head group per XCD; work
//      exactly balanced, 64 blocks each, all resident at 4 blocks/CU).
//      Each XCD's 512KB K+V becomes L2-resident after first touch
//      (stage latency ~600 -> ~200cy).  h = kvh*4 + (j&3); heavy-first
//      qt = 15 - (j>>2).
// In-register P (T12, R11) retained.
// ---------------------------------------------------------------------------
__global__ __launch_bounds__(256, 4) void attn_mfma(const bf16_t* __restrict__ Qm,
                                                    const bf16_t* __restrict__ Km,
                                                    const bf16_t* __restrict__ Vt,
                                                    bf16_t* __restrict__ Om)
{
    const int bid = blockIdx.x;
    const int kvh = bid & 7;                   // XCD-pinned KV head group
    const int j   = bid >> 3;                  // 0..63
    const int h   = kvh * 4 + (j & 3);
    const int qt  = (SEQ / 128 - 1) - (j >> 2);   // heavy-first within XCD
    const int q0  = qt * 128;
    const int t    = threadIdx.x;
    const int w    = t >> 6;
    const int lane = t & 63;
    const int n16  = lane & 15;
    const int q4   = lane >> 4;

    __shared__ alignas(16) bf16_t kb0[64 * 64], kb1[64 * 64];   // K: [kv][d] swz, 8KB each
    __shared__ alignas(16) bf16_t vb0[64 * 64], vb1[64 * 64];   // V: [d][kv] swz

    // Q fragments in registers: rows q0 + w*32 + i*16 + n16 (B-layout for swapped QK)
    bf16x8 qf[2][2];
#pragma unroll
    for (int i = 0; i < 2; ++i) {
        const bf16_t* qp = Qm + (size_t)(q0 + w * 32 + i * 16 + n16) * HID + h * HD;
        qf[i][0] = *(const bf16x8*)(qp + q4 * 8);
        qf[i][1] = *(const bf16x8*)(qp + 32 + q4 * 8);
    }

    f32x4 acc[2][4] = {};
    f32x4 acc_l[2] = {};                 // row-sums of P via ones-MFMA
    const bf16_t one = (bf16_t)1.0f;
    const bf16x8 ones8 = {one, one, one, one, one, one, one, one};

    // staging source addresses (pre-swizzled global col-group, T2 rule #21)
    const int lrow8 = lane >> 3;                 // 0..7
    const int lgrp  = (lane & 7) ^ lrow8;        // source 16B group
    const bf16_t* kgs = Km + (size_t)kvh * HD + (size_t)lrow8 * KVDIM + lgrp * 8;
    const bf16_t* vgs = Vt + (size_t)(kvh * HD + lrow8) * SEQ + lgrp * 8;

    // swizzled fragment-read offsets: logical group g at slot g^(r&7)
    const int rx  = n16 & 7;
    const int xo0 = (q4 ^ rx) * 8;               // groups 0..3
    const int xo1 = ((q4 + 4) ^ rx) * 8;         // groups 4..7

    const int ghmax  = 2 * qt + 1;               // last 64-kv tile staged (odd)
    const int my_last = 2 * qt + (w >> 1);       // last 64-kv tile this wave computes

    auto stage = [&](int gh, bf16_t* kb, bf16_t* vb) {
        const int k0 = gh * 64;
        load_lds16(kgs + (size_t)(k0 + w * 8)      * KVDIM, kb + (w * 8)      * 64);
        load_lds16(kgs + (size_t)(k0 + w * 8 + 32) * KVDIM, kb + (w * 8 + 32) * 64);
        load_lds16(vgs + (size_t)(w * 8)      * SEQ + k0,   vb + (w * 8)      * 64);
        load_lds16(vgs + (size_t)(w * 8 + 32) * SEQ + k0,   vb + (w * 8 + 32) * 64);
    };

    auto compute = [&](int gh, const bf16_t* kbuf, const bf16_t* vbuf) {
        // ---- S^T = K Q (swapped): lane holds S[kv = gh*64+jt*16+q4*4+r][q = ..+i*16+n16] ----
        f32x4 st[2][4];
        __builtin_amdgcn_s_setprio(1);
#pragma unroll
        for (int jt = 0; jt < 4; ++jt) {
            bf16x8 kf0 = *(const bf16x8*)&kbuf[(jt * 16 + n16) * 64 + xo0];
            bf16x8 kf1 = *(const bf16x8*)&kbuf[(jt * 16 + n16) * 64 + xo1];
#pragma unroll
            for (int i = 0; i < 2; ++i) {
                f32x4 s = {};
                s = __builtin_amdgcn_mfma_f32_16x16x32_bf16(kf0, qf[i][0], s, 0, 0, 0);
                s = __builtin_amdgcn_mfma_f32_16x16x32_bf16(kf1, qf[i][1], s, 0, 0, 0);
                st[i][jt] = s;
            }
        }
        __builtin_amdgcn_s_setprio(0);

        // ---- causal mask on the diagonal tile (kv > q) ----
        if (gh == my_last) {
#pragma unroll
            for (int i = 0; i < 2; ++i) {
                int qg = q0 + w * 32 + i * 16 + n16;
#pragma unroll
                for (int jt = 0; jt < 4; ++jt) {
                    int kvb = gh * 64 + jt * 16 + q4 * 4;
#pragma unroll
                    for (int r = 0; r < 4; ++r)
                        if (kvb + r > qg) st[i][jt][r] = -1e30f;
                }
            }
        }

        // ---- exp (raw v_exp_f32 path) ----
#pragma unroll
        for (int i = 0; i < 2; ++i)
#pragma unroll
            for (int jt = 0; jt < 4; ++jt)
#pragma unroll
                for (int r = 0; r < 4; ++r)
                    st[i][jt][r] = EXPFN(st[i][jt][r]);

        // ---- P -> PV A-fragments fully in registers (T12) ----
        bf16x8 pf[2][2];
#pragma unroll
        for (int i = 0; i < 2; ++i) {
#pragma unroll
            for (int hh = 0; hh < 2; ++hh) {
                u32x4 pd;
#pragma unroll
                for (int p = 0; p < 2; ++p) {
                    unsigned int x = cvt_pk_bf16(st[i][2 * hh][2 * p],     st[i][2 * hh][2 * p + 1]);
                    unsigned int y = cvt_pk_bf16(st[i][2 * hh + 1][2 * p], st[i][2 * hh + 1][2 * p + 1]);
                    asm("v_permlane32_swap_b32 %0, %1" : "+v"(x), "+v"(y));
                    asm("v_permlane16_swap_b32 %0, %1" : "+v"(x), "+v"(y));
                    pd[p]     = x;   // Lo[p]
                    pd[2 + p] = y;   // Hi[p]
                }
                pf[i][hh] = *(bf16x8*)&pd;
            }
        }

        __builtin_amdgcn_s_setprio(1);
        // ---- l += row-sum(P) via ones-MFMA ----
#pragma unroll
        for (int i = 0; i < 2; ++i) {
            acc_l[i] = __builtin_amdgcn_mfma_f32_16x16x32_bf16(pf[i][0], ones8, acc_l[i], 0, 0, 0);
            acc_l[i] = __builtin_amdgcn_mfma_f32_16x16x32_bf16(pf[i][1], ones8, acc_l[i], 0, 0, 0);
        }
        // ---- O += P V ----
#pragma unroll
        for (int jd = 0; jd < 4; ++jd) {
            bf16x8 vf0 = *(const bf16x8*)&vbuf[(jd * 16 + n16) * 64 + xo0];
            bf16x8 vf1 = *(const bf16x8*)&vbuf[(jd * 16 + n16) * 64 + xo1];
#pragma unroll
            for (int i = 0; i < 2; ++i) {
                acc[i][jd] = __builtin_amdgcn_mfma_f32_16x16x32_bf16(pf[i][0], vf0, acc[i][jd], 0, 0, 0);
                acc[i][jd] = __builtin_amdgcn_mfma_f32_16x16x32_bf16(pf[i][1], vf1, acc[i][jd], 0, 0, 0);
            }
        }
        __builtin_amdgcn_s_setprio(0);
    };

    // ---- T4 counted-vmcnt pipelined main loop ----
    // Stages 0..ghmax (even count, ghmax odd).  Prologue issues 0,1 (8 loads
    // outstanding/wave).  Each WAITV4 = "my oldest stage landed"; barrier
    // makes that true for ALL waves' loads of that stage.
    stage(0, kb0, vb0);
    stage(1, kb1, vb1);
#pragma unroll 1
    for (int gh = 0; gh < ghmax - 1; gh += 2) {
        WAITV4;
        if (gh <= my_last) compute(gh, kb0, vb0);
        BAR;
        stage(gh + 2, kb0, vb0);
        WAITV4;
        if (gh + 1 <= my_last) compute(gh + 1, kb1, vb1);
        BAR;
        stage(gh + 3, kb1, vb1);          // gh+3 <= ghmax (loop bound)
    }
    WAITV4;
    if (ghmax - 1 <= my_last) compute(ghmax - 1, kb0, vb0);
    BAR;
    WAITV0;
    if (ghmax <= my_last) compute(ghmax, kb1, vb1);

    // ---- normalize + store ----
#pragma unroll
    for (int i = 0; i < 2; ++i) {
        float linv[4];
#pragma unroll
        for (int r = 0; r < 4; ++r) linv[r] = 1.0f / acc_l[i][r];
#pragma unroll
        for (int jd = 0; jd < 4; ++jd)
#pragma unroll
            for (int r = 0; r < 4; ++r) {
                int rowg = q0 + w * 32 + i * 16 + q4 * 4 + r;
                Om[(size_t)rowg * HID + h * HD + jd * 16 + n16] = (bf16_t)(acc[i][jd][r] * linv[r]);
            }
    }
}

// ---------------------------------------------------------------------------
extern "C" void kernel_launch(void* const* d_in, const int* in_sizes, int n_in,
                              void* d_out, int out_size, void* d_ws, size_t ws_size,
                              hipStream_t stream)
{
    const float* X  = (const float*)d_in[0];
    const float* Wq = (const float*)d_in[1];
    const float* Wk = (const float*)d_in[2];
    const float* Wv = (const float*)d_in[3];
    const float* Wo = (const float*)d_in[4];
    float* out = (float*)d_out;

    bf16_t* Xb  = (bf16_t*)d_ws;                      // [SEQ][HID]     8 MB
    bf16_t* Wqb = Xb  + (size_t)NX;                   // [2048][2048]   8 MB
    bf16_t* Wkb = Wqb + (size_t)NWQ;                  // [512][2048]    2 MB
    bf16_t* Wvb = Wkb + (size_t)NWK;                  // [512][2048]    2 MB
    bf16_t* Wob = Wvb + (size_t)NWV;                  // [2048][2048]   8 MB
    bf16_t* Qb  = Wob + (size_t)NWO;                  // [SEQ][NH*HD]   8 MB (pre-scaled QSCALE)
    bf16_t* Kb  = Qb  + (size_t)SEQ * (NH * HD);      // [SEQ][KVDIM]   2 MB
    bf16_t* Vt  = Kb  + (size_t)SEQ * KVDIM;          // [KVDIM][SEQ]   2 MB
    bf16_t* Ob  = Vt  + (size_t)SEQ * KVDIM;          // [SEQ][NH*HD]   8 MB

    // one-shot fp32 -> bf16 conversion of all operands
    cvt_all<<<dim3((NTOT / 8 + 255) / 256), dim3(256), 0, stream>>>(X, Wq, Wk, Wv, Wo, Xb, Wqb, Wkb, Wvb, Wob);

    // fused QKV projection + RoPE (128x128 tiles, XCD-chunked 1D grid of 384)
    qkv_gemm<<<dim3(16 * 24), dim3(512), 0, stream>>>(Xb, Wqb, Wkb, Wvb, Qb, Kb, Vt);

    // causal GQA attention (512 blocks, kvh->XCD pinned, counted-vmcnt)
    attn_mfma<<<dim3((SEQ / 128) * NH), dim3(256), 0, stream>>>(Qb, Kb, Vt, Ob);

    // output projection (128x128 tiles, XCD-chunked 1D grid of 256)
    o_gemm<<<dim3(16 * 16), dim3(512), 0, stream>>>(Ob, Wob, out);
}

// Round 13
// 192.020 us; speedup vs baseline: 1.0212x; 1.0212x over previous
//
#include <hip/hip_runtime.h>
#include <hip/hip_bf16.h>
#include <cstdint>
#include <cstddef>

// Problem constants
#define SEQ   2048
#define HID   2048
#define NH    32
#define NKVH  8
#define HD    64
#define KVDIM (NKVH * HD)   // 512

typedef __bf16 bf16_t;
typedef __bf16 bf16x8 __attribute__((ext_vector_type(8)));
typedef float  f32x4  __attribute__((ext_vector_type(4)));
typedef unsigned int u32x2 __attribute__((ext_vector_type(2)));
typedef unsigned int u32x4 __attribute__((ext_vector_type(4)));

// log2(10000)/32  (RoPE: theta^(-d/32) = exp2(-d*L))
#define ROPE_L 0.4152410118609203f

#if __has_builtin(__builtin_amdgcn_exp2f)
#define QSCALE 0.18033688011112043f
#define EXPFN(x) __builtin_amdgcn_exp2f(x)
#else
#define QSCALE 0.125f
#define EXPFN(x) __expf(x)
#endif

// counted-vmcnt barrier primitives (T4): wave waits for its OLDEST stage's
// loads only; the next stage's loads stay in flight across the barrier.
#define WAITV4  do { asm volatile("s_waitcnt vmcnt(4)" ::: "memory"); \
                     __builtin_amdgcn_sched_barrier(0); \
                     __builtin_amdgcn_s_barrier(); } while (0)
#define WAITV0  do { asm volatile("s_waitcnt vmcnt(0)" ::: "memory"); \
                     __builtin_amdgcn_sched_barrier(0); \
                     __builtin_amdgcn_s_barrier(); } while (0)
#define BAR     __builtin_amdgcn_s_barrier()

__device__ __forceinline__ bf16x8 load8(const float* p) {
    const float4 lo = *(const float4*)p;
    const float4 hi = *(const float4*)(p + 4);
    bf16x8 r;
    r[0] = (bf16_t)lo.x; r[1] = (bf16_t)lo.y; r[2] = (bf16_t)lo.z; r[3] = (bf16_t)lo.w;
    r[4] = (bf16_t)hi.x; r[5] = (bf16_t)hi.y; r[6] = (bf16_t)hi.z; r[7] = (bf16_t)hi.w;
    return r;
}

// async global->LDS, 16B per lane; LDS dest = wave-uniform base + lane*16
__device__ __forceinline__ void load_lds16(const bf16_t* g, bf16_t* l) {
    __builtin_amdgcn_global_load_lds((const __attribute__((address_space(1))) void*)g,
                                     (__attribute__((address_space(3))) void*)l,
                                     16, 0, 0);
}

// pack two f32 -> one dword of 2 bf16 (no builtin on gfx950; T12 recipe, m240)
__device__ __forceinline__ unsigned int cvt_pk_bf16(float lo, float hi) {
    unsigned int r;
    asm("v_cvt_pk_bf16_f32 %0, %1, %2" : "=v"(r) : "v"(lo), "v"(hi));
    return r;
}

// ---------------------------------------------------------------------------
// One-shot fp32 -> bf16 conversion of all GEMM operands.
// ---------------------------------------------------------------------------
#define NX  (SEQ * HID)          // 4M
#define NWQ (NH * HD * HID)      // 4M
#define NWK (KVDIM * HID)        // 1M
#define NWV (KVDIM * HID)        // 1M
#define NWO (HID * NH * HD)      // 4M
#define NTOT (NX + NWQ + NWK + NWV + NWO)   // 14M

__global__ __launch_bounds__(256) void cvt_all(const float* __restrict__ X,
                                               const float* __restrict__ Wq,
                                               const float* __restrict__ Wk,
                                               const float* __restrict__ Wv,
                                               const float* __restrict__ Wo,
                                               bf16_t* __restrict__ Xb,
                                               bf16_t* __restrict__ Wqb,
                                               bf16_t* __restrict__ Wkb,
                                               bf16_t* __restrict__ Wvb,
                                               bf16_t* __restrict__ Wob)
{
    size_t i = ((size_t)blockIdx.x * 256 + threadIdx.x) * 8;
    if (i >= NTOT) return;
    const size_t E0 = NX, E1 = E0 + NWQ, E2 = E1 + NWK, E3 = E2 + NWV;
    const float* s; bf16_t* d; size_t off;
    if (i < E0)      { s = X;  d = Xb;  off = i; }
    else if (i < E1) { s = Wq; d = Wqb; off = i - E0; }
    else if (i < E2) { s = Wk; d = Wkb; off = i - E1; }
    else if (i < E3) { s = Wv; d = Wvb; off = i - E2; }
    else             { s = Wo; d = Wob; off = i - E3; }
    *(bf16x8*)(d + off) = load8(s + off);
}

// ---------------------------------------------------------------------------
// Swizzled-tile convention (T2, both-sides, rule #21):
//   LDS tile = [rows][64] bf16, 128B rows.  Physical 16B slot s of row r
//   holds LOGICAL k-group (s ^ (r&7)).  Staging: linear LDS dest, per-lane
//   pre-swizzled global source.  Reads: slot G ^ (r&7).
//
// XCD swizzle (T1, confirmed R10: qkv 46 -> <40.6us): 1D grid; xcd = bid&7,
// j = bid>>3 indexes a contiguous 2D chunk per XCD so blocks sharing A/B
// panels coalesce in one XCD's L2.
// ---------------------------------------------------------------------------

// ---------------------------------------------------------------------------
// Fused QKV projection + RoPE, 128x128 tiles, 512 threads (8 waves, 4x2
// grid of 32x64 wave-tiles), counted-vmcnt pipeline, XCD-chunked blocks.
// (byte-identical to R10/R11/R12, which passed)
// ---------------------------------------------------------------------------
__global__ __launch_bounds__(512, 4) void qkv_gemm(const bf16_t* __restrict__ Xb,
                                                   const bf16_t* __restrict__ Wqb,
                                                   const bf16_t* __restrict__ Wkb,
                                                   const bf16_t* __restrict__ Wvb,
                                                   bf16_t* __restrict__ Qb,
                                                   bf16_t* __restrict__ Kb,
                                                   bf16_t* __restrict__ Vt)
{
    __shared__ alignas(16) bf16_t sa0[128 * 64], sa1[128 * 64];   // 16KB each
    __shared__ alignas(16) bf16_t sb0[128 * 64], sb1[128 * 64];   // 16KB each
    const int t = threadIdx.x;
    const int lane = t & 63;
    const int w  = t >> 6;               // 0..7
    const int n16 = lane & 15;
    const int q4  = lane >> 4;
    const int wm = (w >> 1) * 32;        // wave tile origin in M (0,32,64,96)
    const int wn = (w & 1) * 64;         // wave tile origin in N (head-aligned)
    f32x4 acc[2][4] = {};

    // ---- T1 XCD-chunked block swizzle: grid 384 = 8 XCDs x (8m x 6n) ----
    const int bid = blockIdx.x;
    const int xcd = bid & 7;
    const int j   = bid >> 3;                    // 0..47
    const int m0 = ((xcd & 1) * 8 + (j & 7)) * 128;     // m-tile 0..15
    const int n0 = ((xcd >> 1) * 6 + (j >> 3)) * 128;   // n-tile 0..23

    const bf16_t* B;
    int mode, nc;
    if (n0 < NH * HD)              { B = Wqb + (size_t)n0 * HID;                     mode = 0; nc = n0; }
    else if (n0 < NH * HD + KVDIM) { B = Wkb + (size_t)(n0 - NH * HD) * HID;         mode = 1; nc = n0 - NH * HD; }
    else                           { B = Wvb + (size_t)(n0 - NH * HD - KVDIM) * HID; mode = 2; nc = n0 - NH * HD - KVDIM; }

    const int lrow8 = lane >> 3;                 // 0..7 (row within 8-row chunk)
    const int lgrp  = (lane & 7) ^ lrow8;        // pre-swizzled source col-group
    const bf16_t* ag = Xb + (size_t)(m0 + w * 16 + lrow8) * HID + lgrp * 8;
    const bf16_t* bg = B  + (size_t)(w * 16 + lrow8) * HID + lgrp * 8;

    auto stage = [&](bf16_t* da, bf16_t* db, int k0) {
        // wave w covers A rows [w*16, w*16+16) and B rows [w*16, w*16+16)
        load_lds16(ag + k0,                      da + (w * 16) * 64);
        load_lds16(ag + (size_t)8 * HID + k0,    da + (w * 16 + 8) * 64);
        load_lds16(bg + k0,                      db + (w * 16) * 64);
        load_lds16(bg + (size_t)8 * HID + k0,    db + (w * 16 + 8) * 64);
    };
    auto mma_step = [&](const bf16_t* sa, const bf16_t* sb) {
#pragma unroll
        for (int kk = 0; kk < 2; ++kk) {
            const int xo = ((kk * 4 + q4) ^ (n16 & 7)) * 8;
            bf16x8 bfrag[4], afrag[2];
#pragma unroll
            for (int j2 = 0; j2 < 4; ++j2)
                bfrag[j2] = *(const bf16x8*)&sb[(wn + j2 * 16 + n16) * 64 + xo];
#pragma unroll
            for (int i = 0; i < 2; ++i)
                afrag[i] = *(const bf16x8*)&sa[(wm + i * 16 + n16) * 64 + xo];
#pragma unroll
            for (int i = 0; i < 2; ++i)
#pragma unroll
                for (int j2 = 0; j2 < 4; ++j2)
                    acc[i][j2] = __builtin_amdgcn_mfma_f32_16x16x32_bf16(afrag[i], bfrag[j2], acc[i][j2], 0, 0, 0);
        }
    };

    // 32 stages of BK=64.  Prologue: stages 0,1.  Loop t issues stage t+2.
    stage(sa0, sb0, 0);
    stage(sa1, sb1, 64);
#pragma unroll 1
    for (int tt = 0; tt < 30; tt += 2) {
        WAITV4;
        mma_step(sa0, sb0);
        BAR;
        stage(sa0, sb0, (tt + 2) * 64);
        WAITV4;
        mma_step(sa1, sb1);
        BAR;
        stage(sa1, sb1, (tt + 3) * 64);
    }
    WAITV4;
    mma_step(sa0, sb0);      // stage 30
    BAR;
    WAITV0;
    mma_step(sa1, sb1);      // stage 31

    if (mode < 2) {
        // ---- RoPE in registers: wave covers one head (wn mult of HD) ----
#pragma unroll
        for (int jt = 0; jt < 2; ++jt) {
            float dd = (float)(jt * 16 + n16);
            float inv = exp2f(-dd * ROPE_L);
#pragma unroll
            for (int i = 0; i < 2; ++i) {
#pragma unroll
                for (int r = 0; r < 4; ++r) {
                    int pos = m0 + wm + i * 16 + q4 * 4 + r;
                    float ang = (float)pos * inv;
                    float sn, cs;
                    sincosf(ang, &sn, &cs);
                    float x1 = acc[i][jt][r], x2 = acc[i][jt + 2][r];
                    acc[i][jt][r]     = x1 * cs - x2 * sn;
                    acc[i][jt + 2][r] = x2 * cs + x1 * sn;
                }
            }
        }
        const float osc = (mode == 0) ? QSCALE : 1.0f;
        bf16_t* dst = (mode == 0) ? Qb : Kb;
        const int ld = (mode == 0) ? NH * HD : KVDIM;
#pragma unroll
        for (int i = 0; i < 2; ++i)
#pragma unroll
            for (int j2 = 0; j2 < 4; ++j2) {
                int row = m0 + wm + i * 16 + q4 * 4;
                int col = nc + wn + j2 * 16 + n16;
#pragma unroll
                for (int r = 0; r < 4; ++r)
                    dst[(size_t)(row + r) * ld + col] = (bf16_t)(acc[i][j2][r] * osc);
            }
    } else {
        // ---- V: store transposed ----
#pragma unroll
        for (int i = 0; i < 2; ++i)
#pragma unroll
            for (int j2 = 0; j2 < 4; ++j2) {
                int row = m0 + wm + i * 16 + q4 * 4;
                int col = nc + wn + j2 * 16 + n16;
#pragma unroll
                for (int r = 0; r < 4; ++r)
                    Vt[(size_t)col * SEQ + row + r] = (bf16_t)acc[i][j2][r];
            }
    }
}

// ---------------------------------------------------------------------------
// O projection: 512-thread 128x128 blocks, grid 256 (1/CU), counted-vmcnt,
// XCD-chunked 8m x 4n blocks.  (byte-identical to R10/R11/R12, which passed)
// ---------------------------------------------------------------------------
__global__ __launch_bounds__(512, 4) void o_gemm(const bf16_t* __restrict__ A,
                                                 const bf16_t* __restrict__ Bw,
                                                 float* __restrict__ C)
{
    __shared__ alignas(16) bf16_t sa0[128 * 64], sa1[128 * 64];
    __shared__ alignas(16) bf16_t sb0[128 * 64], sb1[128 * 64];
    const int t = threadIdx.x;
    const int lane = t & 63;
    const int w  = t >> 6;
    const int n16 = lane & 15;
    const int q4  = lane >> 4;
    const int wm = (w >> 1) * 32;
    const int wn = (w & 1) * 64;
    f32x4 acc[2][4] = {};

    // ---- T1 XCD-chunked swizzle: grid 256 = 8 XCDs x (8m x 4n) ----
    const int bid = blockIdx.x;
    const int xcd = bid & 7;
    const int j   = bid >> 3;                    // 0..31
    const int m0 = ((xcd & 1) * 8 + (j & 7)) * 128;     // m-tile 0..15
    const int n0 = ((xcd >> 1) * 4 + (j >> 3)) * 128;   // n-tile 0..15

    const int lrow8 = lane >> 3;
    const int lgrp  = (lane & 7) ^ lrow8;
    const bf16_t* ag = A  + (size_t)(m0 + w * 16 + lrow8) * HID + lgrp * 8;
    const bf16_t* bg = Bw + (size_t)(n0 + w * 16 + lrow8) * HID + lgrp * 8;

    auto stage = [&](bf16_t* da, bf16_t* db, int k0) {
        load_lds16(ag + k0,                      da + (w * 16) * 64);
        load_lds16(ag + (size_t)8 * HID + k0,    da + (w * 16 + 8) * 64);
        load_lds16(bg + k0,                      db + (w * 16) * 64);
        load_lds16(bg + (size_t)8 * HID + k0,    db + (w * 16 + 8) * 64);
    };
    auto mma_step = [&](const bf16_t* sa, const bf16_t* sb) {
#pragma unroll
        for (int kk = 0; kk < 2; ++kk) {
            const int xo = ((kk * 4 + q4) ^ (n16 & 7)) * 8;
            bf16x8 bfrag[4], afrag[2];
#pragma unroll
            for (int j2 = 0; j2 < 4; ++j2)
                bfrag[j2] = *(const bf16x8*)&sb[(wn + j2 * 16 + n16) * 64 + xo];
#pragma unroll
            for (int i = 0; i < 2; ++i)
                afrag[i] = *(const bf16x8*)&sa[(wm + i * 16 + n16) * 64 + xo];
#pragma unroll
            for (int i = 0; i < 2; ++i)
#pragma unroll
                for (int j2 = 0; j2 < 4; ++j2)
                    acc[i][j2] = __builtin_amdgcn_mfma_f32_16x16x32_bf16(afrag[i], bfrag[j2], acc[i][j2], 0, 0, 0);
        }
    };

    stage(sa0, sb0, 0);
    stage(sa1, sb1, 64);
#pragma unroll 1
    for (int tt = 0; tt < 30; tt += 2) {
        WAITV4;
        mma_step(sa0, sb0);
        BAR;
        stage(sa0, sb0, (tt + 2) * 64);
        WAITV4;
        mma_step(sa1, sb1);
        BAR;
        stage(sa1, sb1, (tt + 3) * 64);
    }
    WAITV4;
    mma_step(sa0, sb0);
    BAR;
    WAITV0;
    mma_step(sa1, sb1);

#pragma unroll
    for (int i = 0; i < 2; ++i)
#pragma unroll
        for (int j2 = 0; j2 < 4; ++j2) {
            int row = m0 + wm + i * 16 + q4 * 4;
            int col = n0 + wn + j2 * 16 + n16;
#pragma unroll
            for (int r = 0; r < 4; ++r)
                C[(size_t)(row + r) * HID + col] = acc[i][j2][r];
        }
}

// ---------------------------------------------------------------------------
// MFMA causal flash attention.  R13 fix: R12's kvh->XCD pinning WORKED
// (FETCH 12.34 -> 8.57 MB = K/V L2-resident) but its qt map broke the
// perfect heavy/light pairing: CU c got qt-sums 24-2(c>>2) (max 24 vs
// mean 17 = +41% critical path = the measured 43-45us).  Restored pairing:
// within each XCD, j<32: qt=15-(j>>1), hs=j&1; j>=32: qt=(j-32)>>1,
// hs=2+(j&1).  CU hosting j and j+32 (same bids as the old bid/bid+256
// pairing) now sums to (16-(j>>1)) + ((j>>1)+1) = 17 for EVERY CU, and
// each (h, qt) pair is covered exactly once.
// Counted-vmcnt pipeline (T4) and in-register P (T12) retained.
// ---------------------------------------------------------------------------
__global__ __launch_bounds__(256, 4) void attn_mfma(const bf16_t* __restrict__ Qm,
                                                    const bf16_t* __restrict__ Km,
                                                    const bf16_t* __restrict__ Vt,
                                                    bf16_t* __restrict__ Om)
{
    const int bid = blockIdx.x;
    const int kvh = bid & 7;                   // XCD-pinned KV head group
    const int j   = bid >> 3;                  // 0..63
    int qt, hs;
    if (j < 32) { qt = 15 - (j >> 1); hs = j & 1; }        // heavy half
    else        { qt = (j - 32) >> 1; hs = 2 + (j & 1); }  // light half
    const int h   = kvh * 4 + hs;
    const int q0  = qt * 128;
    const int t    = threadIdx.x;
    const int w    = t >> 6;
    const int lane = t & 63;
    const int n16  = lane & 15;
    const int q4   = lane >> 4;

    __shared__ alignas(16) bf16_t kb0[64 * 64], kb1[64 * 64];   // K: [kv][d] swz, 8KB each
    __shared__ alignas(16) bf16_t vb0[64 * 64], vb1[64 * 64];   // V: [d][kv] swz

    // Q fragments in registers: rows q0 + w*32 + i*16 + n16 (B-layout for swapped QK)
    bf16x8 qf[2][2];
#pragma unroll
    for (int i = 0; i < 2; ++i) {
        const bf16_t* qp = Qm + (size_t)(q0 + w * 32 + i * 16 + n16) * HID + h * HD;
        qf[i][0] = *(const bf16x8*)(qp + q4 * 8);
        qf[i][1] = *(const bf16x8*)(qp + 32 + q4 * 8);
    }

    f32x4 acc[2][4] = {};
    f32x4 acc_l[2] = {};                 // row-sums of P via ones-MFMA
    const bf16_t one = (bf16_t)1.0f;
    const bf16x8 ones8 = {one, one, one, one, one, one, one, one};

    // staging source addresses (pre-swizzled global col-group, T2 rule #21)
    const int lrow8 = lane >> 3;                 // 0..7
    const int lgrp  = (lane & 7) ^ lrow8;        // source 16B group
    const bf16_t* kgs = Km + (size_t)kvh * HD + (size_t)lrow8 * KVDIM + lgrp * 8;
    const bf16_t* vgs = Vt + (size_t)(kvh * HD + lrow8) * SEQ + lgrp * 8;

    // swizzled fragment-read offsets: logical group g at slot g^(r&7)
    const int rx  = n16 & 7;
    const int xo0 = (q4 ^ rx) * 8;               // groups 0..3
    const int xo1 = ((q4 + 4) ^ rx) * 8;         // groups 4..7

    const int ghmax  = 2 * qt + 1;               // last 64-kv tile staged (odd)
    const int my_last = 2 * qt + (w >> 1);       // last 64-kv tile this wave computes

    auto stage = [&](int gh, bf16_t* kb, bf16_t* vb) {
        const int k0 = gh * 64;
        load_lds16(kgs + (size_t)(k0 + w * 8)      * KVDIM, kb + (w * 8)      * 64);
        load_lds16(kgs + (size_t)(k0 + w * 8 + 32) * KVDIM, kb + (w * 8 + 32) * 64);
        load_lds16(vgs + (size_t)(w * 8)      * SEQ + k0,   vb + (w * 8)      * 64);
        load_lds16(vgs + (size_t)(w * 8 + 32) * SEQ + k0,   vb + (w * 8 + 32) * 64);
    };

    auto compute = [&](int gh, const bf16_t* kbuf, const bf16_t* vbuf) {
        // ---- S^T = K Q (swapped): lane holds S[kv = gh*64+jt*16+q4*4+r][q = ..+i*16+n16] ----
        f32x4 st[2][4];
        __builtin_amdgcn_s_setprio(1);
#pragma unroll
        for (int jt = 0; jt < 4; ++jt) {
            bf16x8 kf0 = *(const bf16x8*)&kbuf[(jt * 16 + n16) * 64 + xo0];
            bf16x8 kf1 = *(const bf16x8*)&kbuf[(jt * 16 + n16) * 64 + xo1];
#pragma unroll
            for (int i = 0; i < 2; ++i) {
                f32x4 s = {};
                s = __builtin_amdgcn_mfma_f32_16x16x32_bf16(kf0, qf[i][0], s, 0, 0, 0);
                s = __builtin_amdgcn_mfma_f32_16x16x32_bf16(kf1, qf[i][1], s, 0, 0, 0);
                st[i][jt] = s;
            }
        }
        __builtin_amdgcn_s_setprio(0);

        // ---- causal mask on the diagonal tile (kv > q) ----
        if (gh == my_last) {
#pragma unroll
            for (int i = 0; i < 2; ++i) {
                int qg = q0 + w * 32 + i * 16 + n16;
#pragma unroll
                for (int jt = 0; jt < 4; ++jt) {
                    int kvb = gh * 64 + jt * 16 + q4 * 4;
#pragma unroll
                    for (int r = 0; r < 4; ++r)
                        if (kvb + r > qg) st[i][jt][r] = -1e30f;
                }
            }
        }

        // ---- exp (raw v_exp_f32 path) ----
#pragma unroll
        for (int i = 0; i < 2; ++i)
#pragma unroll
            for (int jt = 0; jt < 4; ++jt)
#pragma unroll
                for (int r = 0; r < 4; ++r)
                    st[i][jt][r] = EXPFN(st[i][jt][r]);

        // ---- P -> PV A-fragments fully in registers (T12) ----
        bf16x8 pf[2][2];
#pragma unroll
        for (int i = 0; i < 2; ++i) {
#pragma unroll
            for (int hh = 0; hh < 2; ++hh) {
                u32x4 pd;
#pragma unroll
                for (int p = 0; p < 2; ++p) {
                    unsigned int x = cvt_pk_bf16(st[i][2 * hh][2 * p],     st[i][2 * hh][2 * p + 1]);
                    unsigned int y = cvt_pk_bf16(st[i][2 * hh + 1][2 * p], st[i][2 * hh + 1][2 * p + 1]);
                    asm("v_permlane32_swap_b32 %0, %1" : "+v"(x), "+v"(y));
                    asm("v_permlane16_swap_b32 %0, %1" : "+v"(x), "+v"(y));
                    pd[p]     = x;   // Lo[p]
                    pd[2 + p] = y;   // Hi[p]
                }
                pf[i][hh] = *(bf16x8*)&pd;
            }
        }

        __builtin_amdgcn_s_setprio(1);
        // ---- l += row-sum(P) via ones-MFMA ----
#pragma unroll
        for (int i = 0; i < 2; ++i) {
            acc_l[i] = __builtin_amdgcn_mfma_f32_16x16x32_bf16(pf[i][0], ones8, acc_l[i], 0, 0, 0);
            acc_l[i] = __builtin_amdgcn_mfma_f32_16x16x32_bf16(pf[i][1], ones8, acc_l[i], 0, 0, 0);
        }
        // ---- O += P V ----
#pragma unroll
        for (int jd = 0; jd < 4; ++jd) {
            bf16x8 vf0 = *(const bf16x8*)&vbuf[(jd * 16 + n16) * 64 + xo0];
            bf16x8 vf1 = *(const bf16x8*)&vbuf[(jd * 16 + n16) * 64 + xo1];
#pragma unroll
            for (int i = 0; i < 2; ++i) {
                acc[i][jd] = __builtin_amdgcn_mfma_f32_16x16x32_bf16(pf[i][0], vf0, acc[i][jd], 0, 0, 0);
                acc[i][jd] = __builtin_amdgcn_mfma_f32_16x16x32_bf16(pf[i][1], vf1, acc[i][jd], 0, 0, 0);
            }
        }
        __builtin_amdgcn_s_setprio(0);
    };

    // ---- T4 counted-vmcnt pipelined main loop ----
    // Stages 0..ghmax (even count, ghmax odd).  Prologue issues 0,1 (8 loads
    // outstanding/wave).  Each WAITV4 = "my oldest stage landed"; barrier
    // makes that true for ALL waves' loads of that stage.
    stage(0, kb0, vb0);
    stage(1, kb1, vb1);
#pragma unroll 1
    for (int gh = 0; gh < ghmax - 1; gh += 2) {
        WAITV4;
        if (gh <= my_last) compute(gh, kb0, vb0);
        BAR;
        stage(gh + 2, kb0, vb0);
        WAITV4;
        if (gh + 1 <= my_last) compute(gh + 1, kb1, vb1);
        BAR;
        stage(gh + 3, kb1, vb1);          // gh+3 <= ghmax (loop bound)
    }
    WAITV4;
    if (ghmax - 1 <= my_last) compute(ghmax - 1, kb0, vb0);
    BAR;
    WAITV0;
    if (ghmax <= my_last) compute(ghmax, kb1, vb1);

    // ---- normalize + store ----
#pragma unroll
    for (int i = 0; i < 2; ++i) {
        float linv[4];
#pragma unroll
        for (int r = 0; r < 4; ++r) linv[r] = 1.0f / acc_l[i][r];
#pragma unroll
        for (int jd = 0; jd < 4; ++jd)
#pragma unroll
            for (int r = 0; r < 4; ++r) {
                int rowg = q0 + w * 32 + i * 16 + q4 * 4 + r;
                Om[(size_t)rowg * HID + h * HD + jd * 16 + n16] = (bf16_t)(acc[i][jd][r] * linv[r]);
            }
    }
}

// ---------------------------------------------------------------------------
extern "C" void kernel_launch(void* const* d_in, const int* in_sizes, int n_in,
                              void* d_out, int out_size, void* d_ws, size_t ws_size,
                              hipStream_t stream)
{
    const float* X  = (const float*)d_in[0];
    const float* Wq = (const float*)d_in[1];
    const float* Wk = (const float*)d_in[2];
    const float* Wv = (const float*)d_in[3];
    const float* Wo = (const float*)d_in[4];
    float* out = (float*)d_out;

    bf16_t* Xb  = (bf16_t*)d_ws;                      // [SEQ][HID]     8 MB
    bf16_t* Wqb = Xb  + (size_t)NX;                   // [2048][2048]   8 MB
    bf16_t* Wkb = Wqb + (size_t)NWQ;                  // [512][2048]    2 MB
    bf16_t* Wvb = Wkb + (size_t)NWK;                  // [512][2048]    2 MB
    bf16_t* Wob = Wvb + (size_t)NWV;                  // [2048][2048]   8 MB
    bf16_t* Qb  = Wob + (size_t)NWO;                  // [SEQ][NH*HD]   8 MB (pre-scaled QSCALE)
    bf16_t* Kb  = Qb  + (size_t)SEQ * (NH * HD);      // [SEQ][KVDIM]   2 MB
    bf16_t* Vt  = Kb  + (size_t)SEQ * KVDIM;          // [KVDIM][SEQ]   2 MB
    bf16_t* Ob  = Vt  + (size_t)SEQ * KVDIM;          // [SEQ][NH*HD]   8 MB

    // one-shot fp32 -> bf16 conversion of all operands
    cvt_all<<<dim3((NTOT / 8 + 255) / 256), dim3(256), 0, stream>>>(X, Wq, Wk, Wv, Wo, Xb, Wqb, Wkb, Wvb, Wob);

    // fused QKV projection + RoPE (128x128 tiles, XCD-chunked 1D grid of 384)
    qkv_gemm<<<dim3(16 * 24), dim3(512), 0, stream>>>(Xb, Wqb, Wkb, Wvb, Qb, Kb, Vt);

    // causal GQA attention (512 blocks, kvh->XCD pinned, balanced pairing)
    attn_mfma<<<dim3((SEQ / 128) * NH), dim3(256), 0, stream>>>(Qb, Kb, Vt, Ob);

    // output projection (128x128 tiles, XCD-chunked 1D grid of 256)
    o_gemm<<<dim3(16 * 16), dim3(512), 0, stream>>>(Ob, Wob, out);
}